// Round 1
// baseline (268.563 us; speedup 1.0000x reference)
//
#include <hip/hip_runtime.h>

// Problem constants (fixed by reference): B=8, H=32, S=64, C=4096, D=128
#define BB 8
#define HH 32
#define SS 64
#define CC 4096
#define DD 128

// ---------------------------------------------------------------------------
// ws layout (units: 4-byte words)
//   indeg  : 32768          (B*C u32)
//   counts : 64             (B u32, padded)
//   bitmap : 4194304        (B * C*C/32 u32)  -- edge dedupe bits
//   edges  : 16384          (B * 2048 u32 keys i<<12|j)
//   s      : 32768          (B*C f32, sqrt(1+indeg))
//   te     : 16384          (S*256 f32 temporal table)
//   AE     : 4194304        (B*C*D f32, scaled A@E)
//   Eg     : 4194304        (B*C*D f32, relu(AE@W^T+b))
// total ~48.4 MiB
// ---------------------------------------------------------------------------

__global__ void build_edges(const int* __restrict__ hist, unsigned* __restrict__ indeg,
                            unsigned* __restrict__ counts, unsigned* __restrict__ bitmap,
                            unsigned* __restrict__ edges) {
    int t = blockIdx.x * 256 + threadIdx.x;      // [0, B*H*S)
    int s = t & 63;
    if (s == 63) return;                          // last element of each (b,h) row
    int i = hist[t], j = hist[t + 1];
    if (i == j) return;                           // m = (h1!=h2)
    int b = t >> 11;                              // H*S = 2048
    unsigned key = ((unsigned)i << 12) | (unsigned)j;
    unsigned* bm = bitmap + (size_t)b * (CC * (size_t)CC / 32);
    unsigned mask = 1u << (key & 31);
    unsigned old = atomicOr(&bm[key >> 5], mask);
    if (!(old & mask)) {                          // first time this (b,i,j) edge seen
        unsigned e = atomicAdd(&counts[b], 1u);
        edges[b * 2048 + e] = key;
        atomicAdd(&indeg[b * CC + j], 1u);        // column-sum contribution
    }
}

__global__ void compute_s(const unsigned* __restrict__ indeg, float* __restrict__ s) {
    int g = blockIdx.x * 256 + threadIdx.x;       // B*C
    s[g] = sqrtf(1.0f + (float)indeg[g]);
}

__global__ void te_kern(float* __restrict__ te) {
    int g = blockIdx.x * 256 + threadIdx.x;       // S*256
    int t = g >> 8, c = g & 255, k = c >> 1;
    float ang = (float)t * powf(10000.0f, -(float)k / 128.0f);
    te[g] = (c & 1) ? cosf(ang) : sinf(ang);
}

// AE[b,i,:] = s_i^2 * E[b,i,:]   (diagonal term of normalized A)
__global__ void ae_base(const float4* __restrict__ E4, const float* __restrict__ s,
                        float4* __restrict__ AE4) {
    int n = blockIdx.x * 256 + threadIdx.x;       // B*C*32 float4s
    int row = n >> 5;
    float f = s[row]; f *= f;
    float4 e = E4[n];
    AE4[n] = make_float4(e.x * f, e.y * f, e.z * f, e.w * f);
}

// AE[b,i,:] += s_i * s_j * E[b,j,:]  for each unique edge (i->j). One wave/edge.
__global__ void edge_scatter(const float* __restrict__ E, const float* __restrict__ s,
                             const unsigned* __restrict__ counts,
                             const unsigned* __restrict__ edges, float* __restrict__ AE) {
    int w = (blockIdx.x * 256 + threadIdx.x) >> 6;   // wave id, [0, B*2048)
    int lane = threadIdx.x & 63;
    int b = w >> 11, e = w & 2047;
    if ((unsigned)e >= counts[b]) return;
    unsigned key = edges[b * 2048 + e];
    int i = key >> 12, j = key & 4095;
    float coef = s[b * CC + i] * s[b * CC + j];
    const float2 v = ((const float2*)(E + (size_t)(b * CC + j) * DD))[lane];
    float* dst = AE + (size_t)(b * CC + i) * DD;
    atomicAdd(&dst[lane * 2],     coef * v.x);
    atomicAdd(&dst[lane * 2 + 1], coef * v.y);
}

// Eg = relu(AE @ W^T + b).  M=32768, N=K=128.  64-row tiles, K split in halves.
__global__ __launch_bounds__(256) void gemm_relu(const float* __restrict__ AE,
                                                 const float* __restrict__ W,
                                                 const float* __restrict__ bg,
                                                 float* __restrict__ Eg) {
    __shared__ float As[64][69];     // [row][k_local], pad 69 (odd mod 32) for bank spread
    __shared__ float Ws[64][128];    // [k_local][n]
    int r0 = blockIdx.x * 64;
    int tid = threadIdx.x;
    int tr = tid >> 4, tc = tid & 15;             // 16 row-groups x 16 col-groups
    float acc[4][8];
#pragma unroll
    for (int r = 0; r < 4; ++r)
#pragma unroll
        for (int c = 0; c < 8; ++c) acc[r][c] = 0.f;

    for (int kk = 0; kk < 128; kk += 64) {
        __syncthreads();
        for (int idx = tid; idx < 64 * 64; idx += 256) {      // stage AE tile (coalesced)
            int row = idx >> 6, kl = idx & 63;
            As[row][kl] = AE[(size_t)(r0 + row) * 128 + kk + kl];
        }
        for (int idx = tid; idx < 64 * 128; idx += 256) {     // stage W^T slice (L2-hot)
            int kl = idx >> 7, n = idx & 127;
            Ws[kl][n] = W[n * 128 + kk + kl];
        }
        __syncthreads();
#pragma unroll 4
        for (int kl = 0; kl < 64; ++kl) {
            float av[4];
#pragma unroll
            for (int r = 0; r < 4; ++r) av[r] = As[tr * 4 + r][kl];
            const float4* wp = (const float4*)&Ws[kl][tc * 8];
            float4 w0 = wp[0], w1 = wp[1];
            float wv[8] = {w0.x, w0.y, w0.z, w0.w, w1.x, w1.y, w1.z, w1.w};
#pragma unroll
            for (int r = 0; r < 4; ++r)
#pragma unroll
                for (int c = 0; c < 8; ++c)
                    acc[r][c] = fmaf(av[r], wv[c], acc[r][c]);
        }
    }

    float bgv[8];
#pragma unroll
    for (int c = 0; c < 8; ++c) bgv[c] = bg[tc * 8 + c];
#pragma unroll
    for (int r = 0; r < 4; ++r) {
        float4 o0, o1;
        o0.x = fmaxf(acc[r][0] + bgv[0], 0.f);
        o0.y = fmaxf(acc[r][1] + bgv[1], 0.f);
        o0.z = fmaxf(acc[r][2] + bgv[2], 0.f);
        o0.w = fmaxf(acc[r][3] + bgv[3], 0.f);
        o1.x = fmaxf(acc[r][4] + bgv[4], 0.f);
        o1.y = fmaxf(acc[r][5] + bgv[5], 0.f);
        o1.z = fmaxf(acc[r][6] + bgv[6], 0.f);
        o1.w = fmaxf(acc[r][7] + bgv[7], 0.f);
        float* out = Eg + (size_t)(r0 + tr * 4 + r) * 128 + tc * 8;
        ((float4*)out)[0] = o0;
        ((float4*)out)[1] = o1;
    }
}

// fused_hist[b,h,s,:] = [Eg|E][b, hist[b,h,s], :] + te[s,:]; same for fused_cur.
// One wave per output row (256 floats = 64 float4 lanes).
__global__ void gather(const int* __restrict__ hist, const int* __restrict__ cur,
                       const float4* __restrict__ Eg4, const float4* __restrict__ E4,
                       const float4* __restrict__ te4, float4* __restrict__ out4) {
    int g = blockIdx.x * 256 + threadIdx.x;
    int row = g >> 6, lane = g & 63;
    int b, s, cand;
    size_t obase;
    if (row < BB * HH * SS) {
        s = row & 63;
        b = row >> 11;
        cand = hist[row];
        obase = (size_t)row * 64;
    } else {
        int rc = row - BB * HH * SS;
        if (rc >= BB * SS) return;
        s = rc & 63;
        b = rc >> 6;
        cand = cur[rc];
        obase = (size_t)(BB * HH * SS + rc) * 64;
    }
    float4 v = (lane < 32) ? Eg4[(size_t)(b * CC + cand) * 32 + lane]
                           : E4[(size_t)(b * CC + cand) * 32 + (lane - 32)];
    float4 t = te4[s * 64 + lane];
    out4[obase + lane] = make_float4(v.x + t.x, v.y + t.y, v.z + t.z, v.w + t.w);
}

extern "C" void kernel_launch(void* const* d_in, const int* in_sizes, int n_in,
                              void* d_out, int out_size, void* d_ws, size_t ws_size,
                              hipStream_t stream) {
    const int*   hist = (const int*)d_in[1];
    const int*   cur  = (const int*)d_in[2];
    const float* E    = (const float*)d_in[3];
    const float* W    = (const float*)d_in[4];
    const float* bg   = (const float*)d_in[5];
    float* out = (float*)d_out;

    unsigned* ws_u   = (unsigned*)d_ws;
    unsigned* indeg  = ws_u;                         // 32768
    unsigned* counts = indeg + 32768;                // 64
    unsigned* bitmap = counts + 64;                  // 4194304
    unsigned* edges  = bitmap + 4194304;             // 16384
    float*    sarr   = (float*)(edges + 16384);      // 32768
    float*    te     = sarr + 32768;                 // 16384
    float*    AE     = te + 16384;                   // 4194304
    float*    Eg     = AE + 4194304;                 // 4194304

    // zero indeg + counts + bitmap (must be fresh every call)
    hipMemsetAsync(indeg, 0, (size_t)(32768 + 64 + 4194304) * 4, stream);

    build_edges<<<64, 256, 0, stream>>>(hist, indeg, counts, bitmap, edges);
    compute_s<<<128, 256, 0, stream>>>(indeg, sarr);
    te_kern<<<64, 256, 0, stream>>>(te);
    ae_base<<<4096, 256, 0, stream>>>((const float4*)E, sarr, (float4*)AE);
    edge_scatter<<<4096, 256, 0, stream>>>(E, sarr, counts, edges, AE);
    gemm_relu<<<512, 256, 0, stream>>>(AE, W, bg, Eg);
    gather<<<4224, 256, 0, stream>>>(hist, cur, (const float4*)Eg, (const float4*)E,
                                     (const float4*)te, (float4*)out);
}

// Round 2
// 86.584 us; speedup vs baseline: 3.1017x; 3.1017x over previous
//
#include <hip/hip_runtime.h>

// Problem constants (fixed by reference): B=8, H=32, S=64, C=4096, D=128
#define BB 8
#define HH 32
#define SS 64
#define CC 4096
#define DD 128

// ---------------------------------------------------------------------------
// ws layout (units: 4-byte words)
//   indeg  : 32768          (B*C u32)
//   counts : 64             (B u32, padded)
//   bitmap : 4194304        (B * C*C/32 u32)  -- edge dedupe bits
//   edges  : 16384          (B * 2048 u32 keys i<<12|j)
//   s      : 32768          (B*C f32, sqrt(1+indeg))
//   te     : 16384          (S*256 f32 temporal table)
//   AE     : 4194304        (B*C*D f32, scaled A@E)
//   Eg     : 4194304        (B*C*D f32, relu(AE@W^T+b))
// total ~48.4 MiB
// ---------------------------------------------------------------------------

// Wave-aggregated edge builder: dedupe via bitmap atomicOr, then ONE
// atomicAdd(&counts[b]) per wave (not per edge) — kills the single-address
// atomic serialization that cost 186us in R1.
__global__ void build_edges(const int* __restrict__ hist, unsigned* __restrict__ indeg,
                            unsigned* __restrict__ counts, unsigned* __restrict__ bitmap,
                            unsigned* __restrict__ edges) {
    int t = blockIdx.x * 256 + threadIdx.x;      // [0, B*H*S)
    int lane = threadIdx.x & 63;
    int s = t & 63;
    int b = t >> 11;                              // H*S = 2048; constant per wave
    bool need = false;
    unsigned key = 0;
    if (s != 63) {                                // last element of each (b,h) row: no edge
        int i = hist[t], j = hist[t + 1];
        if (i != j) {                             // m = (h1!=h2)
            key = ((unsigned)i << 12) | (unsigned)j;
            unsigned* bm = bitmap + (size_t)b * (CC * (size_t)CC / 32);
            unsigned mask = 1u << (key & 31);
            unsigned old = atomicOr(&bm[key >> 5], mask);
            need = !(old & mask);                 // first time this (b,i,j) edge seen
            if (need) atomicAdd(&indeg[b * CC + j], 1u);   // scattered, low contention
        }
    }
    unsigned long long bal = __ballot(need);
    if (bal == 0ull) return;
    int leader = __ffsll((long long)bal) - 1;
    unsigned base = 0;
    if (lane == leader) base = atomicAdd(&counts[b], (unsigned)__popcll(bal));
    base = __shfl(base, leader);
    if (need) {
        unsigned off = (unsigned)__popcll(bal & ((1ull << lane) - 1ull));
        edges[b * 2048 + base + off] = key;
    }
}

__global__ void compute_s(const unsigned* __restrict__ indeg, float* __restrict__ s) {
    int g = blockIdx.x * 256 + threadIdx.x;       // B*C
    s[g] = sqrtf(1.0f + (float)indeg[g]);
}

__global__ void te_kern(float* __restrict__ te) {
    int g = blockIdx.x * 256 + threadIdx.x;       // S*256
    int t = g >> 8, c = g & 255, k = c >> 1;
    float ang = (float)t * powf(10000.0f, -(float)k / 128.0f);
    te[g] = (c & 1) ? cosf(ang) : sinf(ang);
}

// AE[b,i,:] = s_i^2 * E[b,i,:]   (diagonal term of normalized A)
__global__ void ae_base(const float4* __restrict__ E4, const float* __restrict__ s,
                        float4* __restrict__ AE4) {
    int n = blockIdx.x * 256 + threadIdx.x;       // B*C*32 float4s
    int row = n >> 5;
    float f = s[row]; f *= f;
    float4 e = E4[n];
    AE4[n] = make_float4(e.x * f, e.y * f, e.z * f, e.w * f);
}

// AE[b,i,:] += s_i * s_j * E[b,j,:]  for each unique edge (i->j). One wave/edge.
__global__ void edge_scatter(const float* __restrict__ E, const float* __restrict__ s,
                             const unsigned* __restrict__ counts,
                             const unsigned* __restrict__ edges, float* __restrict__ AE) {
    int w = (blockIdx.x * 256 + threadIdx.x) >> 6;   // wave id, [0, B*2048)
    int lane = threadIdx.x & 63;
    int b = w >> 11, e = w & 2047;
    if ((unsigned)e >= counts[b]) return;
    unsigned key = edges[b * 2048 + e];
    int i = key >> 12, j = key & 4095;
    float coef = s[b * CC + i] * s[b * CC + j];
    const float2 v = ((const float2*)(E + (size_t)(b * CC + j) * DD))[lane];
    float* dst = AE + (size_t)(b * CC + i) * DD;
    atomicAdd(&dst[lane * 2],     coef * v.x);
    atomicAdd(&dst[lane * 2 + 1], coef * v.y);
}

// Eg = relu(AE @ W^T + b).  M=32768, N=K=128.  64-row tiles, K split in halves.
__global__ __launch_bounds__(256) void gemm_relu(const float* __restrict__ AE,
                                                 const float* __restrict__ W,
                                                 const float* __restrict__ bg,
                                                 float* __restrict__ Eg) {
    __shared__ float As[64][69];     // [row][k_local], pad 69 (odd mod 32) for bank spread
    __shared__ float Ws[64][128];    // [k_local][n]
    int r0 = blockIdx.x * 64;
    int tid = threadIdx.x;
    int tr = tid >> 4, tc = tid & 15;             // 16 row-groups x 16 col-groups
    float acc[4][8];
#pragma unroll
    for (int r = 0; r < 4; ++r)
#pragma unroll
        for (int c = 0; c < 8; ++c) acc[r][c] = 0.f;

    for (int kk = 0; kk < 128; kk += 64) {
        __syncthreads();
        for (int idx = tid; idx < 64 * 64; idx += 256) {      // stage AE tile (coalesced)
            int row = idx >> 6, kl = idx & 63;
            As[row][kl] = AE[(size_t)(r0 + row) * 128 + kk + kl];
        }
        for (int idx = tid; idx < 64 * 128; idx += 256) {     // stage W^T slice (L2-hot)
            int kl = idx >> 7, n = idx & 127;
            Ws[kl][n] = W[n * 128 + kk + kl];
        }
        __syncthreads();
#pragma unroll 4
        for (int kl = 0; kl < 64; ++kl) {
            float av[4];
#pragma unroll
            for (int r = 0; r < 4; ++r) av[r] = As[tr * 4 + r][kl];
            const float4* wp = (const float4*)&Ws[kl][tc * 8];
            float4 w0 = wp[0], w1 = wp[1];
            float wv[8] = {w0.x, w0.y, w0.z, w0.w, w1.x, w1.y, w1.z, w1.w};
#pragma unroll
            for (int r = 0; r < 4; ++r)
#pragma unroll
                for (int c = 0; c < 8; ++c)
                    acc[r][c] = fmaf(av[r], wv[c], acc[r][c]);
        }
    }

    float bgv[8];
#pragma unroll
    for (int c = 0; c < 8; ++c) bgv[c] = bg[tc * 8 + c];
#pragma unroll
    for (int r = 0; r < 4; ++r) {
        float4 o0, o1;
        o0.x = fmaxf(acc[r][0] + bgv[0], 0.f);
        o0.y = fmaxf(acc[r][1] + bgv[1], 0.f);
        o0.z = fmaxf(acc[r][2] + bgv[2], 0.f);
        o0.w = fmaxf(acc[r][3] + bgv[3], 0.f);
        o1.x = fmaxf(acc[r][4] + bgv[4], 0.f);
        o1.y = fmaxf(acc[r][5] + bgv[5], 0.f);
        o1.z = fmaxf(acc[r][6] + bgv[6], 0.f);
        o1.w = fmaxf(acc[r][7] + bgv[7], 0.f);
        float* out = Eg + (size_t)(r0 + tr * 4 + r) * 128 + tc * 8;
        ((float4*)out)[0] = o0;
        ((float4*)out)[1] = o1;
    }
}

// fused_hist[b,h,s,:] = [Eg|E][b, hist[b,h,s], :] + te[s,:]; same for fused_cur.
// One wave per output row (256 floats = 64 float4 lanes).
__global__ void gather(const int* __restrict__ hist, const int* __restrict__ cur,
                       const float4* __restrict__ Eg4, const float4* __restrict__ E4,
                       const float4* __restrict__ te4, float4* __restrict__ out4) {
    int g = blockIdx.x * 256 + threadIdx.x;
    int row = g >> 6, lane = g & 63;
    int b, s, cand;
    size_t obase;
    if (row < BB * HH * SS) {
        s = row & 63;
        b = row >> 11;
        cand = hist[row];
        obase = (size_t)row * 64;
    } else {
        int rc = row - BB * HH * SS;
        if (rc >= BB * SS) return;
        s = rc & 63;
        b = rc >> 6;
        cand = cur[rc];
        obase = (size_t)(BB * HH * SS + rc) * 64;
    }
    float4 v = (lane < 32) ? Eg4[(size_t)(b * CC + cand) * 32 + lane]
                           : E4[(size_t)(b * CC + cand) * 32 + (lane - 32)];
    float4 t = te4[s * 64 + lane];
    out4[obase + lane] = make_float4(v.x + t.x, v.y + t.y, v.z + t.z, v.w + t.w);
}

extern "C" void kernel_launch(void* const* d_in, const int* in_sizes, int n_in,
                              void* d_out, int out_size, void* d_ws, size_t ws_size,
                              hipStream_t stream) {
    const int*   hist = (const int*)d_in[1];
    const int*   cur  = (const int*)d_in[2];
    const float* E    = (const float*)d_in[3];
    const float* W    = (const float*)d_in[4];
    const float* bg   = (const float*)d_in[5];
    float* out = (float*)d_out;

    unsigned* ws_u   = (unsigned*)d_ws;
    unsigned* indeg  = ws_u;                         // 32768
    unsigned* counts = indeg + 32768;                // 64
    unsigned* bitmap = counts + 64;                  // 4194304
    unsigned* edges  = bitmap + 4194304;             // 16384
    float*    sarr   = (float*)(edges + 16384);      // 32768
    float*    te     = sarr + 32768;                 // 16384
    float*    AE     = te + 16384;                   // 4194304
    float*    Eg     = AE + 4194304;                 // 4194304

    // zero indeg + counts + bitmap (must be fresh every call)
    hipMemsetAsync(indeg, 0, (size_t)(32768 + 64 + 4194304) * 4, stream);

    build_edges<<<64, 256, 0, stream>>>(hist, indeg, counts, bitmap, edges);
    compute_s<<<128, 256, 0, stream>>>(indeg, sarr);
    te_kern<<<64, 256, 0, stream>>>(te);
    ae_base<<<4096, 256, 0, stream>>>((const float4*)E, sarr, (float4*)AE);
    edge_scatter<<<4096, 256, 0, stream>>>(E, sarr, counts, edges, AE);
    gemm_relu<<<512, 256, 0, stream>>>(AE, W, bg, Eg);
    gather<<<4224, 256, 0, stream>>>(hist, cur, (const float4*)Eg, (const float4*)E,
                                     (const float4*)te, (float4*)out);
}

// Round 3
// 79.463 us; speedup vs baseline: 3.3797x; 1.0896x over previous
//
#include <hip/hip_runtime.h>

// Problem constants (fixed by reference): B=8, H=32, S=64, C=4096, D=128
#define BB 8
#define HH 32
#define SS 64
#define CC 4096
#define DD 128

// ---------------------------------------------------------------------------
// ws layout (units: 4-byte words) — every buffer is write-before-read, so no
// memset/zero-init is needed anywhere (robust to 0xAA poison).
//   counts : 64             (B u32, padded)
//   edges  : 16384          (B * 2048 u32 keys i<<12|j)
//   s      : 32768          (B*C f32, sqrt(1+indeg))
//   te     : 16384          (S*256 f32 temporal table)
//   AE     : 4194304        (B*C*D f32, scaled A@E)
//   Eg     : 4194304        (B*C*D f32, relu(AE@W^T+b))
// total ~32.2 MiB
// ---------------------------------------------------------------------------

// One block per batch. Dedupe the <=2016 candidate edges via an LDS hash set
// (replaces the 16.8MB global bitmap whose 41us memset dominated R2), count
// in-degrees in LDS, and write the full s[b,:] slice + counts + edge list.
__global__ __launch_bounds__(1024) void build_graph(const int* __restrict__ hist,
                                                    unsigned* __restrict__ counts,
                                                    unsigned* __restrict__ edges,
                                                    float* __restrict__ s) {
    __shared__ unsigned table[4096];   // open-addressing hash set of edge keys
    __shared__ unsigned cnt[4096];     // in-degree counters
    __shared__ unsigned total;
    const int b = blockIdx.x;
    const int tid = threadIdx.x;

#pragma unroll
    for (int r = 0; r < 4; ++r) {
        table[tid + r * 1024] = 0xFFFFFFFFu;
        cnt[tid + r * 1024] = 0u;
    }
    if (tid == 0) total = 0u;
    __syncthreads();

    // 2016 candidate edges: t -> (h = t/63, s = t%63)
    for (int t = tid; t < HH * (SS - 1); t += 1024) {
        int h = t / 63, ss = t - h * 63;
        int base = (b * HH + h) * SS + ss;
        int i = hist[base], j = hist[base + 1];
        if (i != j) {
            unsigned key = ((unsigned)i << 12) | (unsigned)j;
            unsigned hh = (key * 2654435761u) >> 20;    // 12-bit hash
            for (;;) {
                hh &= 4095u;
                unsigned old = atomicCAS(&table[hh], 0xFFFFFFFFu, key);
                if (old == 0xFFFFFFFFu) {               // inserted: unique edge
                    unsigned slot = atomicAdd(&total, 1u);
                    edges[b * 2048 + slot] = key;
                    atomicAdd(&cnt[j], 1u);
                    break;
                }
                if (old == key) break;                  // duplicate
                ++hh;
            }
        }
    }
    __syncthreads();

    if (tid == 0) counts[b] = total;
#pragma unroll
    for (int r = 0; r < 4; ++r) {
        int g = tid + r * 1024;
        s[b * CC + g] = sqrtf(1.0f + (float)cnt[g]);
    }
}

__global__ void te_kern(float* __restrict__ te) {
    int g = blockIdx.x * 256 + threadIdx.x;       // S*256
    int t = g >> 8, c = g & 255, k = c >> 1;
    float ang = (float)t * powf(10000.0f, -(float)k / 128.0f);
    te[g] = (c & 1) ? cosf(ang) : sinf(ang);
}

// AE[b,i,:] = s_i^2 * E[b,i,:]   (diagonal term of normalized A)
__global__ void ae_base(const float4* __restrict__ E4, const float* __restrict__ s,
                        float4* __restrict__ AE4) {
    int n = blockIdx.x * 256 + threadIdx.x;       // B*C*32 float4s
    int row = n >> 5;
    float f = s[row]; f *= f;
    float4 e = E4[n];
    AE4[n] = make_float4(e.x * f, e.y * f, e.z * f, e.w * f);
}

// AE[b,i,:] += s_i * s_j * E[b,j,:]  for each unique edge (i->j). One wave/edge.
__global__ void edge_scatter(const float* __restrict__ E, const float* __restrict__ s,
                             const unsigned* __restrict__ counts,
                             const unsigned* __restrict__ edges, float* __restrict__ AE) {
    int w = (blockIdx.x * 256 + threadIdx.x) >> 6;   // wave id, [0, B*2048)
    int lane = threadIdx.x & 63;
    int b = w >> 11, e = w & 2047;
    if ((unsigned)e >= counts[b]) return;
    unsigned key = edges[b * 2048 + e];
    int i = key >> 12, j = key & 4095;
    float coef = s[b * CC + i] * s[b * CC + j];
    const float2 v = ((const float2*)(E + (size_t)(b * CC + j) * DD))[lane];
    float* dst = AE + (size_t)(b * CC + i) * DD;
    atomicAdd(&dst[lane * 2],     coef * v.x);
    atomicAdd(&dst[lane * 2 + 1], coef * v.y);
}

// Eg = relu(AE @ W^T + b).  M=32768, N=K=128.  64-row tiles, K split in halves.
__global__ __launch_bounds__(256) void gemm_relu(const float* __restrict__ AE,
                                                 const float* __restrict__ W,
                                                 const float* __restrict__ bg,
                                                 float* __restrict__ Eg) {
    __shared__ float As[64][69];     // [row][k_local], pad 69 (odd mod 32) for bank spread
    __shared__ float Ws[64][128];    // [k_local][n]
    int r0 = blockIdx.x * 64;
    int tid = threadIdx.x;
    int tr = tid >> 4, tc = tid & 15;             // 16 row-groups x 16 col-groups
    float acc[4][8];
#pragma unroll
    for (int r = 0; r < 4; ++r)
#pragma unroll
        for (int c = 0; c < 8; ++c) acc[r][c] = 0.f;

    for (int kk = 0; kk < 128; kk += 64) {
        __syncthreads();
        for (int idx = tid; idx < 64 * 64; idx += 256) {      // stage AE tile (coalesced)
            int row = idx >> 6, kl = idx & 63;
            As[row][kl] = AE[(size_t)(r0 + row) * 128 + kk + kl];
        }
        for (int idx = tid; idx < 64 * 128; idx += 256) {     // stage W^T slice (L2-hot)
            int kl = idx >> 7, n = idx & 127;
            Ws[kl][n] = W[n * 128 + kk + kl];
        }
        __syncthreads();
#pragma unroll 4
        for (int kl = 0; kl < 64; ++kl) {
            float av[4];
#pragma unroll
            for (int r = 0; r < 4; ++r) av[r] = As[tr * 4 + r][kl];
            const float4* wp = (const float4*)&Ws[kl][tc * 8];
            float4 w0 = wp[0], w1 = wp[1];
            float wv[8] = {w0.x, w0.y, w0.z, w0.w, w1.x, w1.y, w1.z, w1.w};
#pragma unroll
            for (int r = 0; r < 4; ++r)
#pragma unroll
                for (int c = 0; c < 8; ++c)
                    acc[r][c] = fmaf(av[r], wv[c], acc[r][c]);
        }
    }

    float bgv[8];
#pragma unroll
    for (int c = 0; c < 8; ++c) bgv[c] = bg[tc * 8 + c];
#pragma unroll
    for (int r = 0; r < 4; ++r) {
        float4 o0, o1;
        o0.x = fmaxf(acc[r][0] + bgv[0], 0.f);
        o0.y = fmaxf(acc[r][1] + bgv[1], 0.f);
        o0.z = fmaxf(acc[r][2] + bgv[2], 0.f);
        o0.w = fmaxf(acc[r][3] + bgv[3], 0.f);
        o1.x = fmaxf(acc[r][4] + bgv[4], 0.f);
        o1.y = fmaxf(acc[r][5] + bgv[5], 0.f);
        o1.z = fmaxf(acc[r][6] + bgv[6], 0.f);
        o1.w = fmaxf(acc[r][7] + bgv[7], 0.f);
        float* out = Eg + (size_t)(r0 + tr * 4 + r) * 128 + tc * 8;
        ((float4*)out)[0] = o0;
        ((float4*)out)[1] = o1;
    }
}

// fused_hist[b,h,s,:] = [Eg|E][b, hist[b,h,s], :] + te[s,:]; same for fused_cur.
// One wave per output row (256 floats = 64 float4 lanes).
__global__ void gather(const int* __restrict__ hist, const int* __restrict__ cur,
                       const float4* __restrict__ Eg4, const float4* __restrict__ E4,
                       const float4* __restrict__ te4, float4* __restrict__ out4) {
    int g = blockIdx.x * 256 + threadIdx.x;
    int row = g >> 6, lane = g & 63;
    int b, s, cand;
    size_t obase;
    if (row < BB * HH * SS) {
        s = row & 63;
        b = row >> 11;
        cand = hist[row];
        obase = (size_t)row * 64;
    } else {
        int rc = row - BB * HH * SS;
        if (rc >= BB * SS) return;
        s = rc & 63;
        b = rc >> 6;
        cand = cur[rc];
        obase = (size_t)(BB * HH * SS + rc) * 64;
    }
    float4 v = (lane < 32) ? Eg4[(size_t)(b * CC + cand) * 32 + lane]
                           : E4[(size_t)(b * CC + cand) * 32 + (lane - 32)];
    float4 t = te4[s * 64 + lane];
    out4[obase + lane] = make_float4(v.x + t.x, v.y + t.y, v.z + t.z, v.w + t.w);
}

extern "C" void kernel_launch(void* const* d_in, const int* in_sizes, int n_in,
                              void* d_out, int out_size, void* d_ws, size_t ws_size,
                              hipStream_t stream) {
    const int*   hist = (const int*)d_in[1];
    const int*   cur  = (const int*)d_in[2];
    const float* E    = (const float*)d_in[3];
    const float* W    = (const float*)d_in[4];
    const float* bg   = (const float*)d_in[5];
    float* out = (float*)d_out;

    unsigned* ws_u   = (unsigned*)d_ws;
    unsigned* counts = ws_u;                         // 64
    unsigned* edges  = counts + 64;                  // 16384
    float*    sarr   = (float*)(edges + 16384);      // 32768
    float*    te     = sarr + 32768;                 // 16384
    float*    AE     = te + 16384;                   // 4194304
    float*    Eg     = AE + 4194304;                 // 4194304

    build_graph<<<BB, 1024, 0, stream>>>(hist, counts, edges, sarr);
    te_kern<<<64, 256, 0, stream>>>(te);
    ae_base<<<4096, 256, 0, stream>>>((const float4*)E, sarr, (float4*)AE);
    edge_scatter<<<4096, 256, 0, stream>>>(E, sarr, counts, edges, AE);
    gemm_relu<<<512, 256, 0, stream>>>(AE, W, bg, Eg);
    gather<<<4224, 256, 0, stream>>>(hist, cur, (const float4*)Eg, (const float4*)E,
                                     (const float4*)te, (float4*)out);
}

// Round 4
// 69.431 us; speedup vs baseline: 3.8681x; 1.1445x over previous
//
#include <hip/hip_runtime.h>

// Problem constants (fixed by reference): B=8, H=32, S=64, C=4096, D=128
#define BB 8
#define HH 32
#define SS 64
#define CC 4096
#define DD 128

// ---------------------------------------------------------------------------
// ws layout (units: 4-byte words) — every buffer is write-before-read, so no
// memset/zero-init is needed anywhere (robust to 0xAA poison).
//   rowptr : 32832          (B * 4104, CSR row pointers per batch; [4096]=total)
//   adj    : 16384          (B * 2048 u32 dest columns, grouped by source row)
//   s      : 32768          (B*C f32, sqrt(1+indeg))
//   te     : 16384          (S*256 f32 temporal table)
//   AE     : 4194304        (B*C*D f32, normalized A@E)
//   Eg     : 4194304        (B*C*D f32, relu(AE@W^T+b))
// ---------------------------------------------------------------------------

// One block (1024 thr) per batch. Dedupe the <=2016 candidate edges via an LDS
// hash set, count in/out degrees in LDS, prefix-scan out-degrees into CSR
// rowptr, scatter adjacency, and write s[b,:] = sqrt(1+indeg).
__global__ __launch_bounds__(1024) void build_graph(const int* __restrict__ hist,
                                                    unsigned* __restrict__ rowptr,
                                                    unsigned* __restrict__ adj,
                                                    float* __restrict__ s) {
    __shared__ unsigned table[4096];    // open-addressing hash set of edge keys
    __shared__ unsigned cnt_in[4096];   // in-degree counters, later scatter cursors
    __shared__ unsigned cnt_out[4096];  // out-degree counters
    __shared__ unsigned rptr[4096];     // exclusive prefix of cnt_out
    __shared__ unsigned lkeys[2048];    // unique edge keys
    __shared__ unsigned wbase[17];
    __shared__ unsigned total;
    const int b = blockIdx.x;
    const int tid = threadIdx.x;

#pragma unroll
    for (int r = 0; r < 4; ++r) {
        int g = tid + r * 1024;
        table[g] = 0xFFFFFFFFu;
        cnt_in[g] = 0u;
        cnt_out[g] = 0u;
    }
    if (tid == 0) total = 0u;
    __syncthreads();

    // 2016 candidate edges: t -> (h = t/63, s = t%63)
    for (int t = tid; t < HH * (SS - 1); t += 1024) {
        int h = t / 63, ss = t - h * 63;
        int base = (b * HH + h) * SS + ss;
        int i = hist[base], j = hist[base + 1];
        if (i != j) {
            unsigned key = ((unsigned)i << 12) | (unsigned)j;
            unsigned hh = (key * 2654435761u) >> 20;    // 12-bit hash
            for (;;) {
                hh &= 4095u;
                unsigned old = atomicCAS(&table[hh], 0xFFFFFFFFu, key);
                if (old == 0xFFFFFFFFu) {               // inserted: unique edge
                    unsigned slot = atomicAdd(&total, 1u);
                    lkeys[slot] = key;
                    atomicAdd(&cnt_in[key & 4095u], 1u);
                    atomicAdd(&cnt_out[key >> 12], 1u);
                    break;
                }
                if (old == key) break;                  // duplicate
                ++hh;
            }
        }
    }
    __syncthreads();

    // s[b,:] from in-degree; wave-level inclusive scan of per-thread sums
#pragma unroll
    for (int r = 0; r < 4; ++r) {
        int g = tid + r * 1024;
        s[b * CC + g] = sqrtf(1.0f + (float)cnt_in[g]);
    }
    unsigned v0 = cnt_out[tid * 4], v1 = cnt_out[tid * 4 + 1];
    unsigned v2 = cnt_out[tid * 4 + 2], v3 = cnt_out[tid * 4 + 3];
    unsigned tsum = v0 + v1 + v2 + v3;
    int lane = tid & 63, wv = tid >> 6;                 // 16 waves
    unsigned x = tsum;
#pragma unroll
    for (int off = 1; off < 64; off <<= 1) {
        unsigned y = __shfl_up(x, off);
        if (lane >= off) x += y;
    }
    if (lane == 63) wbase[wv + 1] = x;                  // wave total
    __syncthreads();
    if (tid == 0) {
        wbase[0] = 0u;
        for (int w = 1; w <= 16; ++w) wbase[w] += wbase[w - 1];
    }
    __syncthreads();
    unsigned texcl = wbase[wv] + x - tsum;              // exclusive prefix for this thread
    rptr[tid * 4]     = texcl;
    rptr[tid * 4 + 1] = texcl + v0;
    rptr[tid * 4 + 2] = texcl + v0 + v1;
    rptr[tid * 4 + 3] = texcl + v0 + v1 + v2;
#pragma unroll
    for (int r = 0; r < 4; ++r) cnt_in[tid + r * 1024] = 0u;   // reuse as cursors
    __syncthreads();

    for (int e = tid; e < (int)total; e += 1024) {
        unsigned key = lkeys[e];
        unsigned i = key >> 12, j = key & 4095u;
        unsigned pos = rptr[i] + atomicAdd(&cnt_in[i], 1u);
        adj[b * 2048 + pos] = j;
    }
#pragma unroll
    for (int r = 0; r < 4; ++r) {
        int g = tid + r * 1024;
        rowptr[b * 4104 + g] = rptr[g];
    }
    if (tid == 0) rowptr[b * 4104 + 4096] = total;
}

__global__ void te_kern(float* __restrict__ te) {
    int g = blockIdx.x * 256 + threadIdx.x;       // S*256
    int t = g >> 8, c = g & 255, k = c >> 1;
    float ang = (float)t * powf(10000.0f, -(float)k / 128.0f);
    te[g] = (c & 1) ? cosf(ang) : sinf(ang);
}

// AE[b,i,:] = s_i*(s_i*E[i,:] + sum_{i->j} s_j*E[j,:])  — atomic-free CSR gather.
// One wave per row, float2 per lane. Replaces R3's ae_base + edge_scatter
// (~2M contended global atomics, est. ~40us).
__global__ __launch_bounds__(256) void ae_rows(const float* __restrict__ E,
                                               const float* __restrict__ s,
                                               const unsigned* __restrict__ rowptr,
                                               const unsigned* __restrict__ adj,
                                               float* __restrict__ AE) {
    int w = (blockIdx.x * 256 + threadIdx.x) >> 6;   // row id = b*4096+i, [0, 32768)
    int lane = threadIdx.x & 63;
    int b = w >> 12, i = w & 4095;
    const unsigned* rp = rowptr + b * 4104;
    unsigned p0 = rp[i], p1 = rp[i + 1];
    float si = s[w];
    const float2* Eb = (const float2*)(E + (size_t)b * CC * DD);
    float2 e = Eb[(size_t)i * 64 + lane];
    float2 acc = make_float2(si * e.x, si * e.y);
    for (unsigned p = p0; p < p1; ++p) {
        unsigned j = adj[b * 2048 + p];
        float sj = s[b * CC + j];
        float2 ej = Eb[(size_t)j * 64 + lane];
        acc.x += sj * ej.x;
        acc.y += sj * ej.y;
    }
    ((float2*)AE)[(size_t)w * 64 + lane] = make_float2(si * acc.x, si * acc.y);
}

// Eg = relu(AE @ W^T + b).  M=32768, N=K=128.  64-row tiles, K split in halves.
__global__ __launch_bounds__(256) void gemm_relu(const float* __restrict__ AE,
                                                 const float* __restrict__ W,
                                                 const float* __restrict__ bg,
                                                 float* __restrict__ Eg) {
    __shared__ float As[64][69];     // [row][k_local], pad 69 (odd mod 32) for bank spread
    __shared__ float Ws[64][128];    // [k_local][n]
    int r0 = blockIdx.x * 64;
    int tid = threadIdx.x;
    int tr = tid >> 4, tc = tid & 15;             // 16 row-groups x 16 col-groups
    float acc[4][8];
#pragma unroll
    for (int r = 0; r < 4; ++r)
#pragma unroll
        for (int c = 0; c < 8; ++c) acc[r][c] = 0.f;

    for (int kk = 0; kk < 128; kk += 64) {
        __syncthreads();
        for (int idx = tid; idx < 64 * 64; idx += 256) {      // stage AE tile (coalesced)
            int row = idx >> 6, kl = idx & 63;
            As[row][kl] = AE[(size_t)(r0 + row) * 128 + kk + kl];
        }
        for (int idx = tid; idx < 64 * 128; idx += 256) {     // stage W^T slice (L2-hot)
            int kl = idx >> 7, n = idx & 127;
            Ws[kl][n] = W[n * 128 + kk + kl];
        }
        __syncthreads();
#pragma unroll 4
        for (int kl = 0; kl < 64; ++kl) {
            float av[4];
#pragma unroll
            for (int r = 0; r < 4; ++r) av[r] = As[tr * 4 + r][kl];
            const float4* wp = (const float4*)&Ws[kl][tc * 8];
            float4 w0 = wp[0], w1 = wp[1];
            float wv[8] = {w0.x, w0.y, w0.z, w0.w, w1.x, w1.y, w1.z, w1.w};
#pragma unroll
            for (int r = 0; r < 4; ++r)
#pragma unroll
                for (int c = 0; c < 8; ++c)
                    acc[r][c] = fmaf(av[r], wv[c], acc[r][c]);
        }
    }

    float bgv[8];
#pragma unroll
    for (int c = 0; c < 8; ++c) bgv[c] = bg[tc * 8 + c];
#pragma unroll
    for (int r = 0; r < 4; ++r) {
        float4 o0, o1;
        o0.x = fmaxf(acc[r][0] + bgv[0], 0.f);
        o0.y = fmaxf(acc[r][1] + bgv[1], 0.f);
        o0.z = fmaxf(acc[r][2] + bgv[2], 0.f);
        o0.w = fmaxf(acc[r][3] + bgv[3], 0.f);
        o1.x = fmaxf(acc[r][4] + bgv[4], 0.f);
        o1.y = fmaxf(acc[r][5] + bgv[5], 0.f);
        o1.z = fmaxf(acc[r][6] + bgv[6], 0.f);
        o1.w = fmaxf(acc[r][7] + bgv[7], 0.f);
        float* out = Eg + (size_t)(r0 + tr * 4 + r) * 128 + tc * 8;
        ((float4*)out)[0] = o0;
        ((float4*)out)[1] = o1;
    }
}

// fused_hist[b,h,s,:] = [Eg|E][b, hist[b,h,s], :] + te[s,:]; same for fused_cur.
// One wave per output row (256 floats = 64 float4 lanes).
__global__ void gather(const int* __restrict__ hist, const int* __restrict__ cur,
                       const float4* __restrict__ Eg4, const float4* __restrict__ E4,
                       const float4* __restrict__ te4, float4* __restrict__ out4) {
    int g = blockIdx.x * 256 + threadIdx.x;
    int row = g >> 6, lane = g & 63;
    int b, s, cand;
    size_t obase;
    if (row < BB * HH * SS) {
        s = row & 63;
        b = row >> 11;
        cand = hist[row];
        obase = (size_t)row * 64;
    } else {
        int rc = row - BB * HH * SS;
        if (rc >= BB * SS) return;
        s = rc & 63;
        b = rc >> 6;
        cand = cur[rc];
        obase = (size_t)(BB * HH * SS + rc) * 64;
    }
    float4 v = (lane < 32) ? Eg4[(size_t)(b * CC + cand) * 32 + lane]
                           : E4[(size_t)(b * CC + cand) * 32 + (lane - 32)];
    float4 t = te4[s * 64 + lane];
    out4[obase + lane] = make_float4(v.x + t.x, v.y + t.y, v.z + t.z, v.w + t.w);
}

extern "C" void kernel_launch(void* const* d_in, const int* in_sizes, int n_in,
                              void* d_out, int out_size, void* d_ws, size_t ws_size,
                              hipStream_t stream) {
    const int*   hist = (const int*)d_in[1];
    const int*   cur  = (const int*)d_in[2];
    const float* E    = (const float*)d_in[3];
    const float* W    = (const float*)d_in[4];
    const float* bg   = (const float*)d_in[5];
    float* out = (float*)d_out;

    unsigned* ws_u   = (unsigned*)d_ws;
    unsigned* rowptr = ws_u;                         // 32832
    unsigned* adj    = rowptr + 32832;               // 16384
    float*    sarr   = (float*)(adj + 16384);        // 32768
    float*    te     = sarr + 32768;                 // 16384
    float*    AE     = te + 16384;                   // 4194304
    float*    Eg     = AE + 4194304;                 // 4194304

    build_graph<<<BB, 1024, 0, stream>>>(hist, rowptr, adj, sarr);
    te_kern<<<64, 256, 0, stream>>>(te);
    ae_rows<<<8192, 256, 0, stream>>>(E, sarr, rowptr, adj, AE);
    gemm_relu<<<512, 256, 0, stream>>>(AE, W, bg, Eg);
    gather<<<4224, 256, 0, stream>>>(hist, cur, (const float4*)Eg, (const float4*)E,
                                     (const float4*)te, (float4*)out);
}

// Round 5
// 56.037 us; speedup vs baseline: 4.7926x; 1.2390x over previous
//
#include <hip/hip_runtime.h>

// Problem constants (fixed by reference): B=8, H=32, S=64, C=4096, D=128
#define BB 8
#define HH 32
#define SS 64
#define CC 4096
#define DD 128
#define MAXU 2176   // per-batch compacted-row stride (max used = 2048+64 <= 2112)

// ---------------------------------------------------------------------------
// ws layout (units: 4-byte words) — every buffer is write-before-read, no
// zero-init needed anywhere (robust to 0xAA poison).
//   rowptr : 32832   (B*4104 CSR row pointers; [4096] = total edges)
//   adj    : 16384   (B*2048 dest columns, grouped by source row)
//   s      : 32768   (B*C f32, sqrt(1+indeg))
//   te     : 16384   (S*256 f32 temporal table)
//   remap  : 32768   (B*C u32, candidate -> compact slot)
//   inv    : 17408   (B*MAXU u32, compact slot -> candidate)
//   nused  : 64      (B u32, # used candidates)
//   Eg_c   : 2228224 (B*MAXU*D f32, compacted relu(AE@W^T+b))
// ---------------------------------------------------------------------------

// Blocks 0..7: per-batch graph build. Dedupe <=2016 edges via LDS hash set,
// count in/out degrees, mark USED candidates (those referenced by hist/cur),
// single packed prefix-scan -> CSR rowptr + compact slot map. Blocks 8..23:
// temporal-embedding table (fused to save a launch).
__global__ __launch_bounds__(1024) void build_graph(const int* __restrict__ hist,
                                                    const int* __restrict__ cur,
                                                    unsigned* __restrict__ rowptr,
                                                    unsigned* __restrict__ adj,
                                                    float* __restrict__ s,
                                                    unsigned* __restrict__ remap,
                                                    unsigned* __restrict__ inv,
                                                    unsigned* __restrict__ nused,
                                                    float* __restrict__ te) {
    const int tid = threadIdx.x;
    if (blockIdx.x >= BB) {                        // te table: 16 blocks x 1024
        int g = (blockIdx.x - BB) * 1024 + tid;    // S*256 = 16384
        int t = g >> 8, c = g & 255, k = c >> 1;
        float ang = (float)t * powf(10000.0f, -(float)k / 128.0f);
        te[g] = (c & 1) ? cosf(ang) : sinf(ang);
        return;
    }
    __shared__ unsigned table[4096];    // hash set of edge keys
    __shared__ unsigned cnt_in[4096];   // in-degree, later scatter cursors
    __shared__ unsigned cnt_out[4096];  // out-degree
    __shared__ unsigned used[4096];     // candidate referenced by hist/cur?
    __shared__ unsigned pref[4096];     // packed exclusive prefix
    __shared__ unsigned lkeys[2048];    // unique edge keys
    __shared__ unsigned wbase[17];
    __shared__ unsigned total;
    const int b = blockIdx.x;

#pragma unroll
    for (int r = 0; r < 4; ++r) {
        int g = tid + r * 1024;
        table[g] = 0xFFFFFFFFu;
        cnt_in[g] = 0u;
        cnt_out[g] = 0u;
        used[g] = 0u;
    }
    if (tid == 0) total = 0u;
    __syncthreads();

    // mark used candidates
    for (int t = tid; t < HH * SS; t += 1024) used[hist[b * HH * SS + t]] = 1u;
    if (tid < SS) used[cur[b * SS + tid]] = 1u;

    // dedupe edges: t -> (h = t/63, s = t%63)
    for (int t = tid; t < HH * (SS - 1); t += 1024) {
        int h = t / 63, ss = t - h * 63;
        int base = (b * HH + h) * SS + ss;
        int i = hist[base], j = hist[base + 1];
        if (i != j) {
            unsigned key = ((unsigned)i << 12) | (unsigned)j;
            unsigned hh = (key * 2654435761u) >> 20;
            for (;;) {
                hh &= 4095u;
                unsigned old = atomicCAS(&table[hh], 0xFFFFFFFFu, key);
                if (old == 0xFFFFFFFFu) {
                    unsigned slot = atomicAdd(&total, 1u);
                    lkeys[slot] = key;
                    atomicAdd(&cnt_in[key & 4095u], 1u);
                    atomicAdd(&cnt_out[key >> 12], 1u);
                    break;
                }
                if (old == key) break;
                ++hh;
            }
        }
    }
    __syncthreads();

    // s[b,:] from in-degree
#pragma unroll
    for (int r = 0; r < 4; ++r) {
        int g = tid + r * 1024;
        s[b * CC + g] = sqrtf(1.0f + (float)cnt_in[g]);
    }

    // packed scan: v = (out_degree << 13) | used.  Prefix of both at once.
    unsigned v0 = (cnt_out[tid * 4]     << 13) | used[tid * 4];
    unsigned v1 = (cnt_out[tid * 4 + 1] << 13) | used[tid * 4 + 1];
    unsigned v2 = (cnt_out[tid * 4 + 2] << 13) | used[tid * 4 + 2];
    unsigned v3 = (cnt_out[tid * 4 + 3] << 13) | used[tid * 4 + 3];
    unsigned tsum = v0 + v1 + v2 + v3;
    int lane = tid & 63, wv = tid >> 6;            // 16 waves
    unsigned x = tsum;
#pragma unroll
    for (int off = 1; off < 64; off <<= 1) {
        unsigned y = __shfl_up(x, off);
        if (lane >= off) x += y;
    }
    if (lane == 63) wbase[wv + 1] = x;
    __syncthreads();
    if (tid == 0) {
        wbase[0] = 0u;
        for (int w = 1; w <= 16; ++w) wbase[w] += wbase[w - 1];
    }
    __syncthreads();
    unsigned texcl = wbase[wv] + x - tsum;
    pref[tid * 4]     = texcl;
    pref[tid * 4 + 1] = texcl + v0;
    pref[tid * 4 + 2] = texcl + v0 + v1;
    pref[tid * 4 + 3] = texcl + v0 + v1 + v2;
#pragma unroll
    for (int r = 0; r < 4; ++r) cnt_in[tid + r * 1024] = 0u;  // reuse as cursors
    __syncthreads();

    // emit rowptr / remap / inv
#pragma unroll
    for (int r = 0; r < 4; ++r) {
        int g = tid + r * 1024;
        unsigned p = pref[g];
        rowptr[b * 4104 + g] = p >> 13;
        unsigned slot = p & 8191u;
        remap[b * CC + g] = slot;
        if (used[g]) inv[b * MAXU + slot] = (unsigned)g;
    }
    if (tid == 0) {
        unsigned grand = wbase[16];
        rowptr[b * 4104 + 4096] = grand >> 13;
        nused[b] = grand & 8191u;
    }

    // scatter adjacency in CSR order
    for (int e = tid; e < (int)total; e += 1024) {
        unsigned key = lkeys[e];
        unsigned i = key >> 12, j = key & 4095u;
        unsigned pos = (pref[i] >> 13) + atomicAdd(&cnt_in[i], 1u);
        adj[b * 2048 + pos] = j;
    }
}

// Fused, compacted: for each USED row i: ae = s_i*(s_i*E[i] + sum_{i->j} s_j*E[j])
// (CSR gather into LDS), then Eg_c[slot] = relu(ae @ W^T + bias).
// 256 threads, 32 rows/block. Replaces ae_rows + gemm_relu and skips the ~59%
// of rows never referenced by the output gathers.
__global__ __launch_bounds__(256) void ae_gemm(const float* __restrict__ E,
                                               const float* __restrict__ s,
                                               const unsigned* __restrict__ rowptr,
                                               const unsigned* __restrict__ adj,
                                               const unsigned* __restrict__ inv,
                                               const unsigned* __restrict__ nused,
                                               const float* __restrict__ W,
                                               const float* __restrict__ bg,
                                               float* __restrict__ Eg_c) {
    __shared__ float As[32][132];   // ae rows; stride 132: rows 4 banks apart
    __shared__ float Ws[64][132];   // W^T half-slice [k][n]
    const int b = blockIdx.x / 66;
    const int s0 = (blockIdx.x % 66) * 32;
    const unsigned nu = nused[b];
    if ((unsigned)s0 >= nu) return;               // block-uniform early out
    const int tid = threadIdx.x;
    const int lane = tid & 63, wv = tid >> 6;     // 4 waves

    // phase 1: build 32 ae rows (one wave per row, 8 rows per wave, float2 lanes)
    const float2* Eb = (const float2*)(E + (size_t)b * CC * DD);
    const unsigned* rp = rowptr + b * 4104;
#pragma unroll
    for (int q = 0; q < 8; ++q) {
        int row = wv * 8 + q;
        unsigned slot = (unsigned)(s0 + row);
        float2 acc = make_float2(0.f, 0.f);
        if (slot < nu) {
            unsigned c = inv[b * MAXU + slot];
            float si = s[b * CC + c];
            float2 e = Eb[(size_t)c * 64 + lane];
            acc.x = si * e.x; acc.y = si * e.y;
            unsigned p0 = rp[c], p1 = rp[c + 1];
            for (unsigned p = p0; p < p1; ++p) {
                unsigned j = adj[b * 2048 + p];
                float sj = s[b * CC + j];
                float2 ej = Eb[(size_t)j * 64 + lane];
                acc.x += sj * ej.x; acc.y += sj * ej.y;
            }
            acc.x *= si; acc.y *= si;
        }
        ((float2*)&As[row][0])[lane] = acc;
    }

    const int tr = tid >> 4, tc = tid & 15;       // 16 row-groups x 16 col-groups
    float bgv[8];
#pragma unroll
    for (int c = 0; c < 8; ++c) bgv[c] = bg[tc * 8 + c];
    float acc[2][8];
#pragma unroll
    for (int r = 0; r < 2; ++r)
#pragma unroll
        for (int c = 0; c < 8; ++c) acc[r][c] = 0.f;

    // phase 2: Eg = relu(As @ W^T + b), K staged in halves
    for (int kk = 0; kk < 128; kk += 64) {
        __syncthreads();
        for (int idx = tid; idx < 64 * 128; idx += 256) {   // stage W slice
            int kl = idx >> 7, n = idx & 127;               // LDS writes 2-way (free)
            Ws[kl][n] = W[n * 128 + kk + kl];               // global uncoalesced, L2-hot
        }
        __syncthreads();
#pragma unroll 4
        for (int kl = 0; kl < 64; ++kl) {
            float av[2];
#pragma unroll
            for (int r = 0; r < 2; ++r) av[r] = As[tr * 2 + r][kk + kl];
            const float4* wp = (const float4*)&Ws[kl][tc * 8];
            float4 w0 = wp[0], w1 = wp[1];
            float wvv[8] = {w0.x, w0.y, w0.z, w0.w, w1.x, w1.y, w1.z, w1.w};
#pragma unroll
            for (int r = 0; r < 2; ++r)
#pragma unroll
                for (int c = 0; c < 8; ++c)
                    acc[r][c] = fmaf(av[r], wvv[c], acc[r][c]);
        }
    }

#pragma unroll
    for (int r = 0; r < 2; ++r) {
        unsigned slot = (unsigned)(s0 + tr * 2 + r);
        if (slot >= nu) continue;
        float4 o0, o1;
        o0.x = fmaxf(acc[r][0] + bgv[0], 0.f);
        o0.y = fmaxf(acc[r][1] + bgv[1], 0.f);
        o0.z = fmaxf(acc[r][2] + bgv[2], 0.f);
        o0.w = fmaxf(acc[r][3] + bgv[3], 0.f);
        o1.x = fmaxf(acc[r][4] + bgv[4], 0.f);
        o1.y = fmaxf(acc[r][5] + bgv[5], 0.f);
        o1.z = fmaxf(acc[r][6] + bgv[6], 0.f);
        o1.w = fmaxf(acc[r][7] + bgv[7], 0.f);
        float* out = Eg_c + ((size_t)b * MAXU + slot) * 128 + tc * 8;
        ((float4*)out)[0] = o0;
        ((float4*)out)[1] = o1;
    }
}

// out[row,:] = [Eg_c[slot]|E[cand]] + te[s,:].  One wave per output row.
__global__ void gather(const int* __restrict__ hist, const int* __restrict__ cur,
                       const unsigned* __restrict__ remap,
                       const float4* __restrict__ Egc4, const float4* __restrict__ E4,
                       const float4* __restrict__ te4, float4* __restrict__ out4) {
    int g = blockIdx.x * 256 + threadIdx.x;
    int row = g >> 6, lane = g & 63;
    int b, s, cand;
    size_t obase;
    if (row < BB * HH * SS) {
        s = row & 63;
        b = row >> 11;
        cand = hist[row];
        obase = (size_t)row * 64;
    } else {
        int rc = row - BB * HH * SS;
        if (rc >= BB * SS) return;
        s = rc & 63;
        b = rc >> 6;
        cand = cur[rc];
        obase = (size_t)(BB * HH * SS + rc) * 64;
    }
    unsigned slot = remap[b * CC + cand];
    float4 v = (lane < 32) ? Egc4[((size_t)b * MAXU + slot) * 32 + lane]
                           : E4[(size_t)(b * CC + cand) * 32 + (lane - 32)];
    float4 t = te4[s * 64 + lane];
    out4[obase + lane] = make_float4(v.x + t.x, v.y + t.y, v.z + t.z, v.w + t.w);
}

extern "C" void kernel_launch(void* const* d_in, const int* in_sizes, int n_in,
                              void* d_out, int out_size, void* d_ws, size_t ws_size,
                              hipStream_t stream) {
    const int*   hist = (const int*)d_in[1];
    const int*   cur  = (const int*)d_in[2];
    const float* E    = (const float*)d_in[3];
    const float* W    = (const float*)d_in[4];
    const float* bg   = (const float*)d_in[5];
    float* out = (float*)d_out;

    unsigned* ws_u   = (unsigned*)d_ws;
    unsigned* rowptr = ws_u;                         // 32832
    unsigned* adj    = rowptr + 32832;               // 16384
    float*    sarr   = (float*)(adj + 16384);        // 32768
    float*    te     = sarr + 32768;                 // 16384
    unsigned* remap  = (unsigned*)(te + 16384);      // 32768
    unsigned* inv    = remap + 32768;                // 17408
    unsigned* nused  = inv + 17408;                  // 64
    float*    Eg_c   = (float*)(nused + 64);         // 2228224

    build_graph<<<BB + 16, 1024, 0, stream>>>(hist, cur, rowptr, adj, sarr,
                                              remap, inv, nused, te);
    ae_gemm<<<BB * 66, 256, 0, stream>>>(E, sarr, rowptr, adj, inv, nused, W, bg, Eg_c);
    gather<<<4224, 256, 0, stream>>>(hist, cur, remap, (const float4*)Eg_c,
                                     (const float4*)E, (const float4*)te, (float4*)out);
}

// Round 6
// 54.370 us; speedup vs baseline: 4.9396x; 1.0307x over previous
//
#include <hip/hip_runtime.h>

// Problem constants (fixed by reference): B=8, H=32, S=64, C=4096, D=128
#define BB 8
#define HH 32
#define SS 64
#define CC 4096
#define DD 128
#define MAXU 2176   // per-batch compacted stride (used <= 2112, occ == 2112)

// ---------------------------------------------------------------------------
// ws layout (units: 4-byte words) — every buffer write-before-read, no memset.
//   rowptr   : 32832   (B*4104 CSR edge row pointers; [4096]=total)
//   adj      : 16384   (B*2048 dest cols, CSR order)
//   s        : 32768   (B*C f32 sqrt(1+indeg))
//   te       : 16384   (S*256 f32 temporal table)
//   inv      : 17408   (B*MAXU slot -> candidate)
//   nused    : 64      (B u32)
//   occp     : 32832   (B*4104 occurrence CSR ptrs per candidate)
//   occ_list : 17408   (B*MAXU entries (outrow<<6|s))
//   Wt       : 16384   (W transposed, Wt[k*128+n] = W[n*128+k])
// ---------------------------------------------------------------------------

// Blocks 0..7: per-batch graph build (edge dedupe + CSR + used-compaction +
// occurrence CSR). Blocks 8..23: te table. Blocks 24..39: W transpose.
__global__ __launch_bounds__(1024) void build_graph(const int* __restrict__ hist,
                                                    const int* __restrict__ cur,
                                                    const float* __restrict__ W,
                                                    unsigned* __restrict__ rowptr,
                                                    unsigned* __restrict__ adj,
                                                    float* __restrict__ s,
                                                    unsigned* __restrict__ inv,
                                                    unsigned* __restrict__ nused,
                                                    unsigned* __restrict__ occp,
                                                    unsigned* __restrict__ occ_list,
                                                    float* __restrict__ te,
                                                    float* __restrict__ Wt) {
    const int tid = threadIdx.x;
    if (blockIdx.x >= BB + 16) {                   // W transpose: 16 blocks
        int g = (blockIdx.x - BB - 16) * 1024 + tid;   // 16384 elems
        int k = g >> 7, n = g & 127;
        Wt[g] = W[n * 128 + k];
        return;
    }
    if (blockIdx.x >= BB) {                        // te table: 16 blocks
        int g = (blockIdx.x - BB) * 1024 + tid;    // S*256 = 16384
        int t = g >> 8, c = g & 255, k = c >> 1;
        float ang = (float)t * powf(10000.0f, -(float)k / 128.0f);
        te[g] = (c & 1) ? cosf(ang) : sinf(ang);
        return;
    }
    __shared__ unsigned table[4096];    // hash set of edge keys
    __shared__ unsigned cnt_a[4096];    // in-degree; later scatter cursors
    __shared__ unsigned cnt_b[4096];    // out-degree; later occurrence counts
    __shared__ unsigned used[4096];
    __shared__ unsigned pref[4096];
    __shared__ unsigned lkeys[2048];
    __shared__ unsigned wbase[17];
    __shared__ unsigned total;
    const int b = blockIdx.x;
    const int lane = tid & 63, wv = tid >> 6;

#pragma unroll
    for (int r = 0; r < 4; ++r) {
        int g = tid + r * 1024;
        table[g] = 0xFFFFFFFFu;
        cnt_a[g] = 0u;
        cnt_b[g] = 0u;
        used[g] = 0u;
    }
    if (tid == 0) total = 0u;
    __syncthreads();

    for (int t = tid; t < HH * SS; t += 1024) used[hist[b * HH * SS + t]] = 1u;
    if (tid < SS) used[cur[b * SS + tid]] = 1u;

    for (int t = tid; t < HH * (SS - 1); t += 1024) {   // edge dedupe
        int h = t / 63, ss = t - h * 63;
        int base = (b * HH + h) * SS + ss;
        int i = hist[base], j = hist[base + 1];
        if (i != j) {
            unsigned key = ((unsigned)i << 12) | (unsigned)j;
            unsigned hh = (key * 2654435761u) >> 20;
            for (;;) {
                hh &= 4095u;
                unsigned old = atomicCAS(&table[hh], 0xFFFFFFFFu, key);
                if (old == 0xFFFFFFFFu) {
                    unsigned slot = atomicAdd(&total, 1u);
                    lkeys[slot] = key;
                    atomicAdd(&cnt_a[key & 4095u], 1u);
                    atomicAdd(&cnt_b[key >> 12], 1u);
                    break;
                }
                if (old == key) break;
                ++hh;
            }
        }
    }
    __syncthreads();

#pragma unroll
    for (int r = 0; r < 4; ++r) {                  // s from in-degree
        int g = tid + r * 1024;
        s[b * CC + g] = sqrtf(1.0f + (float)cnt_a[g]);
    }

    // ---- scan #1 (packed): v = (outdeg<<13)|used -> CSR rowptr + slot map
    {
        unsigned v0 = (cnt_b[tid * 4]     << 13) | used[tid * 4];
        unsigned v1 = (cnt_b[tid * 4 + 1] << 13) | used[tid * 4 + 1];
        unsigned v2 = (cnt_b[tid * 4 + 2] << 13) | used[tid * 4 + 2];
        unsigned v3 = (cnt_b[tid * 4 + 3] << 13) | used[tid * 4 + 3];
        unsigned tsum = v0 + v1 + v2 + v3;
        unsigned x = tsum;
#pragma unroll
        for (int off = 1; off < 64; off <<= 1) {
            unsigned y = __shfl_up(x, off);
            if (lane >= off) x += y;
        }
        if (lane == 63) wbase[wv + 1] = x;
        __syncthreads();
        if (tid == 0) {
            wbase[0] = 0u;
            for (int w = 1; w <= 16; ++w) wbase[w] += wbase[w - 1];
        }
        __syncthreads();
        unsigned texcl = wbase[wv] + x - tsum;
        pref[tid * 4]     = texcl;
        pref[tid * 4 + 1] = texcl + v0;
        pref[tid * 4 + 2] = texcl + v0 + v1;
        pref[tid * 4 + 3] = texcl + v0 + v1 + v2;
    }
#pragma unroll
    for (int r = 0; r < 4; ++r) cnt_a[tid + r * 1024] = 0u;   // scatter cursors
    __syncthreads();

#pragma unroll
    for (int r = 0; r < 4; ++r) {
        int g = tid + r * 1024;
        unsigned p = pref[g];
        rowptr[b * 4104 + g] = p >> 13;
        if (used[g]) inv[b * MAXU + (p & 8191u)] = (unsigned)g;
    }
    if (tid == 0) {
        rowptr[b * 4104 + 4096] = wbase[16] >> 13;
        nused[b] = wbase[16] & 8191u;
    }
    for (int e = tid; e < (int)total; e += 1024) { // adjacency scatter
        unsigned key = lkeys[e];
        unsigned i = key >> 12, j = key & 4095u;
        unsigned pos = (pref[i] >> 13) + atomicAdd(&cnt_a[i], 1u);
        adj[b * 2048 + pos] = j;
    }
    __syncthreads();

    // ---- occurrence counting
#pragma unroll
    for (int r = 0; r < 4; ++r) cnt_b[tid + r * 1024] = 0u;
    __syncthreads();
    for (int t = tid; t < HH * SS; t += 1024) atomicAdd(&cnt_b[hist[b * HH * SS + t]], 1u);
    if (tid < SS) atomicAdd(&cnt_b[cur[b * SS + tid]], 1u);
    __syncthreads();

    // ---- scan #2 (plain) over occurrence counts -> occp
    {
        unsigned v0 = cnt_b[tid * 4], v1 = cnt_b[tid * 4 + 1];
        unsigned v2 = cnt_b[tid * 4 + 2], v3 = cnt_b[tid * 4 + 3];
        unsigned tsum = v0 + v1 + v2 + v3;
        unsigned x = tsum;
#pragma unroll
        for (int off = 1; off < 64; off <<= 1) {
            unsigned y = __shfl_up(x, off);
            if (lane >= off) x += y;
        }
        if (lane == 63) wbase[wv + 1] = x;
        __syncthreads();
        if (tid == 0) {
            wbase[0] = 0u;
            for (int w = 1; w <= 16; ++w) wbase[w] += wbase[w - 1];
        }
        __syncthreads();
        unsigned texcl = wbase[wv] + x - tsum;
        pref[tid * 4]     = texcl;
        pref[tid * 4 + 1] = texcl + v0;
        pref[tid * 4 + 2] = texcl + v0 + v1;
        pref[tid * 4 + 3] = texcl + v0 + v1 + v2;
    }
#pragma unroll
    for (int r = 0; r < 4; ++r) cnt_a[tid + r * 1024] = 0u;   // occ cursors
    __syncthreads();

#pragma unroll
    for (int r = 0; r < 4; ++r) {
        int g = tid + r * 1024;
        occp[b * 4104 + g] = pref[g];
    }
    if (tid == 0) occp[b * 4104 + 4096] = wbase[16];

    for (int t = tid; t < HH * SS; t += 1024) {    // hist occurrences
        int cand = hist[b * HH * SS + t];
        unsigned pos = pref[cand] + atomicAdd(&cnt_a[cand], 1u);
        occ_list[b * MAXU + pos] = ((unsigned)(b * 2048 + t) << 6) | (unsigned)(t & 63);
    }
    if (tid < SS) {                                // cur occurrences
        int cand = cur[b * SS + tid];
        unsigned pos = pref[cand] + atomicAdd(&cnt_a[cand], 1u);
        occ_list[b * MAXU + pos] =
            ((unsigned)(BB * HH * SS + b * SS + tid) << 6) | (unsigned)tid;
    }
}

// Fused tail: per 32 compacted rows — CSR-gather ae (edge-parallel, LDS
// atomics), GEMM vs W^T, relu+bias, then write every output occurrence
// [eg | E] + te directly to d_out. Replaces ae_gemm + gather + Eg_c traffic.
__global__ __launch_bounds__(256) void fused_tail(const float* __restrict__ E,
                                                  const float* __restrict__ s,
                                                  const unsigned* __restrict__ rowptr,
                                                  const unsigned* __restrict__ adj,
                                                  const unsigned* __restrict__ inv,
                                                  const unsigned* __restrict__ nused,
                                                  const float* __restrict__ Wt,
                                                  const float* __restrict__ bg,
                                                  const unsigned* __restrict__ occp,
                                                  const unsigned* __restrict__ occ_list,
                                                  const float* __restrict__ te,
                                                  float* __restrict__ out) {
    __shared__ float As[32][132];    // ae rows, then eg rows (16B-aligned stride)
    __shared__ float Es[32][128];    // raw E rows (second half of outputs)
    __shared__ float Ws[64][128];    // W^T half-slice
    __shared__ unsigned eq[2048];    // edge queue (r<<12|j)
    __shared__ unsigned c_l[32];
    __shared__ float si_l[32];
    __shared__ unsigned eqn;
    const int b = blockIdx.x / 66;
    const int s0 = (blockIdx.x % 66) * 32;
    const unsigned nu = nused[b];
    if ((unsigned)s0 >= nu) return;
    const int tid = threadIdx.x;
    const int lane = tid & 63, wv = tid >> 6;

    if (tid == 0) eqn = 0u;
    if (tid < 32) {
        unsigned slot = (unsigned)(s0 + tid);
        unsigned c = 0xFFFFFFFFu; float si = 0.f;
        if (slot < nu) { c = inv[b * MAXU + slot]; si = s[b * CC + c]; }
        c_l[tid] = c; si_l[tid] = si;
    }
    __syncthreads();

    if (tid < 32) {                                // push edges of my row
        unsigned c = c_l[tid];
        if (c != 0xFFFFFFFFu) {
            unsigned p0 = rowptr[b * 4104 + c], p1 = rowptr[b * 4104 + c + 1];
            for (unsigned p = p0; p < p1; ++p) {
                unsigned pos = atomicAdd(&eqn, 1u);
                eq[pos] = ((unsigned)tid << 12) | adj[b * 2048 + p];
            }
        }
    }
    const float2* Eb = (const float2*)(E + (size_t)b * CC * DD);
#pragma unroll
    for (int q = 0; q < 8; ++q) {                  // base rows (independent loads)
        int r = wv * 8 + q;
        unsigned c = c_l[r];
        float2 e = make_float2(0.f, 0.f);
        if (c != 0xFFFFFFFFu) e = Eb[(size_t)c * 64 + lane];
        ((float2*)&Es[r][0])[lane] = e;
        float si = si_l[r];
        ((float2*)&As[r][0])[lane] = make_float2(si * e.x, si * e.y);
    }
    __syncthreads();

    unsigned ne = eqn;                             // edge-parallel accumulate
    for (unsigned ei = (unsigned)wv; ei < ne; ei += 4) {
        unsigned ent = eq[ei];
        unsigned r = ent >> 12, j = ent & 4095u;
        float sj = s[b * CC + j];
        float2 ej = Eb[(size_t)j * 64 + lane];
        atomicAdd(&As[r][lane * 2],     sj * ej.x);
        atomicAdd(&As[r][lane * 2 + 1], sj * ej.y);
    }
    __syncthreads();
#pragma unroll
    for (int q = 0; q < 8; ++q) {                  // final scale by s_i
        int r = wv * 8 + q;
        float si = si_l[r];
        float2 v = ((float2*)&As[r][0])[lane];
        ((float2*)&As[r][0])[lane] = make_float2(si * v.x, si * v.y);
    }

    const int tr = tid >> 4, tc = tid & 15;
    float bgv[8];
#pragma unroll
    for (int c = 0; c < 8; ++c) bgv[c] = bg[tc * 8 + c];
    float acc[2][8];
#pragma unroll
    for (int r = 0; r < 2; ++r)
#pragma unroll
        for (int c = 0; c < 8; ++c) acc[r][c] = 0.f;

    for (int kk = 0; kk < 128; kk += 64) {         // GEMM vs staged W^T
        __syncthreads();
        for (int idx = tid; idx < 64 * 128; idx += 256) {
            int kl = idx >> 7, n = idx & 127;
            Ws[kl][n] = Wt[(kk + kl) * 128 + n];   // coalesced (pre-transposed)
        }
        __syncthreads();
#pragma unroll 4
        for (int kl = 0; kl < 64; ++kl) {
            float av[2];
#pragma unroll
            for (int r = 0; r < 2; ++r) av[r] = As[tr * 2 + r][kk + kl];
            const float4* wp = (const float4*)&Ws[kl][tc * 8];
            float4 w0 = wp[0], w1 = wp[1];
            float wvv[8] = {w0.x, w0.y, w0.z, w0.w, w1.x, w1.y, w1.z, w1.w};
#pragma unroll
            for (int r = 0; r < 2; ++r)
#pragma unroll
                for (int c = 0; c < 8; ++c)
                    acc[r][c] = fmaf(av[r], wvv[c], acc[r][c]);
        }
    }
    __syncthreads();                               // all As reads done
#pragma unroll
    for (int r = 0; r < 2; ++r) {                  // eg -> As (bias+relu)
        int row = tr * 2 + r;
        float4 o0, o1;
        o0.x = fmaxf(acc[r][0] + bgv[0], 0.f);
        o0.y = fmaxf(acc[r][1] + bgv[1], 0.f);
        o0.z = fmaxf(acc[r][2] + bgv[2], 0.f);
        o0.w = fmaxf(acc[r][3] + bgv[3], 0.f);
        o1.x = fmaxf(acc[r][4] + bgv[4], 0.f);
        o1.y = fmaxf(acc[r][5] + bgv[5], 0.f);
        o1.z = fmaxf(acc[r][6] + bgv[6], 0.f);
        o1.w = fmaxf(acc[r][7] + bgv[7], 0.f);
        ((float4*)&As[row][0])[tc * 2]     = o0;
        ((float4*)&As[row][0])[tc * 2 + 1] = o1;
    }
    __syncthreads();

    const float4* te4 = (const float4*)te;         // occurrence writes
    float4* out4 = (float4*)out;
#pragma unroll
    for (int q = 0; q < 8; ++q) {
        int r = wv * 8 + q;
        unsigned c = c_l[r];
        if (c == 0xFFFFFFFFu) continue;
        unsigned o0 = occp[b * 4104 + c], o1 = occp[b * 4104 + c + 1];
        float4 v = (lane < 32) ? ((const float4*)&As[r][0])[lane]
                               : ((const float4*)&Es[r][0])[lane - 32];
        for (unsigned o = o0; o < o1; ++o) {
            unsigned ent = occ_list[b * MAXU + o];
            unsigned outrow = ent >> 6, spos = ent & 63u;
            float4 t = te4[spos * 64 + lane];
            out4[(size_t)outrow * 64 + lane] =
                make_float4(v.x + t.x, v.y + t.y, v.z + t.z, v.w + t.w);
        }
    }
}

extern "C" void kernel_launch(void* const* d_in, const int* in_sizes, int n_in,
                              void* d_out, int out_size, void* d_ws, size_t ws_size,
                              hipStream_t stream) {
    const int*   hist = (const int*)d_in[1];
    const int*   cur  = (const int*)d_in[2];
    const float* E    = (const float*)d_in[3];
    const float* W    = (const float*)d_in[4];
    const float* bg   = (const float*)d_in[5];
    float* out = (float*)d_out;

    unsigned* ws_u     = (unsigned*)d_ws;
    unsigned* rowptr   = ws_u;                       // 32832
    unsigned* adj      = rowptr + 32832;             // 16384
    float*    sarr     = (float*)(adj + 16384);      // 32768
    float*    te       = sarr + 32768;               // 16384
    unsigned* inv      = (unsigned*)(te + 16384);    // 17408
    unsigned* nused    = inv + 17408;                // 64
    unsigned* occp     = nused + 64;                 // 32832
    unsigned* occ_list = occp + 32832;               // 17408
    float*    Wt       = (float*)(occ_list + 17408); // 16384

    build_graph<<<BB + 32, 1024, 0, stream>>>(hist, cur, W, rowptr, adj, sarr,
                                              inv, nused, occp, occ_list, te, Wt);
    fused_tail<<<BB * 66, 256, 0, stream>>>(E, sarr, rowptr, adj, inv, nused,
                                            Wt, bg, occp, occ_list, te, out);
}